// Round 4
// baseline (717.506 us; speedup 1.0000x reference)
//
#include <hip/hip_runtime.h>
#include <hip/hip_bf16.h>
#include <stdint.h>

#define M_NODES 100000
#define NE      300000
#define D       256
#define D2      512
#define NLAYERS 4

typedef float  f32x4  __attribute__((ext_vector_type(4)));
typedef __bf16 bf16x8 __attribute__((ext_vector_type(8)));

static __device__ __forceinline__ float bf2f(uint32_t u) {
  union { uint32_t i; float f; } v; v.i = u << 16; return v.f;
}
static __device__ __forceinline__ uint32_t f2bf(float f) {
  union { float f; uint32_t i; } v; v.f = f;
  return (v.i + 0x7fffu + ((v.i >> 16) & 1u)) >> 16;
}
static __device__ __forceinline__ void gload_lds16(const void* g, void* l) {
  __builtin_amdgcn_global_load_lds((const __attribute__((address_space(1))) uint32_t*)g,
                                   (__attribute__((address_space(3))) uint32_t*)l, 16, 0, 0);
}

// ---------------- CSR build ----------------
__global__ void hist_kernel(const int* __restrict__ rows, int* __restrict__ counts) {
  int e = blockIdx.x * 256 + threadIdx.x;
  if (e < NE) atomicAdd(&counts[rows[e]], 1);
}

__global__ void scan1_kernel(const int* __restrict__ counts, int* __restrict__ rp,
                             int* __restrict__ bsum) {
  __shared__ int sd[256];
  int tid = threadIdx.x;
  int base = blockIdx.x * 1024 + tid * 4;
  int v0 = (base + 0 < M_NODES) ? counts[base + 0] : 0;
  int v1 = (base + 1 < M_NODES) ? counts[base + 1] : 0;
  int v2 = (base + 2 < M_NODES) ? counts[base + 2] : 0;
  int v3 = (base + 3 < M_NODES) ? counts[base + 3] : 0;
  int tsum = v0 + v1 + v2 + v3;
  sd[tid] = tsum; __syncthreads();
  for (int off = 1; off < 256; off <<= 1) {
    int x = sd[tid];
    if (tid >= off) x += sd[tid - off];
    __syncthreads(); sd[tid] = x; __syncthreads();
  }
  int excl = sd[tid] - tsum;
  if (base + 0 < M_NODES) rp[base + 0] = excl; excl += v0;
  if (base + 1 < M_NODES) rp[base + 1] = excl; excl += v1;
  if (base + 2 < M_NODES) rp[base + 2] = excl; excl += v2;
  if (base + 3 < M_NODES) rp[base + 3] = excl;
  if (tid == 255) bsum[blockIdx.x] = sd[255];
}

__global__ void scan2_kernel(const int* __restrict__ bsum, int* __restrict__ boff) {
  __shared__ int sd[128];
  int tid = threadIdx.x;
  int v = (tid < 98) ? bsum[tid] : 0;
  sd[tid] = v; __syncthreads();
  for (int off = 1; off < 128; off <<= 1) {
    int x = sd[tid];
    if (tid >= off) x += sd[tid - off];
    __syncthreads(); sd[tid] = x; __syncthreads();
  }
  if (tid < 98) boff[tid] = sd[tid] - v;
}

__global__ void scan3_kernel(int* __restrict__ rp, const int* __restrict__ boff,
                             int* __restrict__ cursor) {
  int i = blockIdx.x * 256 + threadIdx.x;
  if (i > M_NODES) return;
  int v = (i < M_NODES) ? rp[i] + boff[i >> 10] : NE;
  rp[i] = v;
  if (i < M_NODES) cursor[i] = v;
}

__global__ void scatter_kernel(const int* __restrict__ rows, const int* __restrict__ cols,
                               const float* __restrict__ vals, int* __restrict__ cursor,
                               int* __restrict__ e_col, float* __restrict__ e_val) {
  int e = blockIdx.x * 256 + threadIdx.x;
  if (e >= NE) return;
  int r = rows[e];
  int p = atomicAdd(&cursor[r], 1);
  e_col[p] = cols[e];
  e_val[p] = vals[e];
}

// ---------------- x prep: bf16 h + f32 copy into out right half ----------------
__global__ void prep_x_kernel(const float* __restrict__ x, ushort* __restrict__ h,
                              float* __restrict__ out) {
  size_t idx = (size_t)blockIdx.x * 256 + threadIdx.x;  // M*D/4 threads
  size_t i = idx >> 6; int c = (int)(idx & 63) * 4;
  float4 v = *(const float4*)(x + i * D + c);
  *(float4*)(out + i * D2 + D + c) = v;
  ushort4 o;
  o.x = (ushort)f2bf(v.x); o.y = (ushort)f2bf(v.y);
  o.z = (ushort)f2bf(v.z); o.w = (ushort)f2bf(v.w);
  *(ushort4*)(h + i * D + c) = o;
}

// Bt[layer][n][k] = bf16( n<256 ? W[layer][k][n] : SW[layer][k][n-256] )
__global__ void conv_w_kernel(const float* __restrict__ W, const float* __restrict__ SW,
                              ushort* __restrict__ Bt) {
  int idx = blockIdx.x * 256 + threadIdx.x;  // 4*512*256 = 524288
  if (idx >= NLAYERS * D2 * D) return;
  int k = idx & (D - 1);
  int n = (idx >> 8) & (D2 - 1);
  int layer = idx >> 17;
  float v = (n < D) ? W[(size_t)layer * D * D + k * D + n]
                    : SW[(size_t)layer * D * D + k * D + (n - D)];
  Bt[idx] = (ushort)f2bf(v);
}

// ---------------- GEMM: [M,256](bf16) x [256,512](bf16, N-major) -> AB [M,512](bf16) ----------------
#define BM 128
#define BN 128
#define BK 64

__global__ __launch_bounds__(256, 2)
void gemm_kernel(const ushort* __restrict__ h, const ushort* __restrict__ Bt,
                 ushort* __restrict__ outAB) {
  __shared__ __align__(16) ushort As[BM * BK];  // [128][64], row = 128B
  __shared__ __align__(16) ushort Bs[BN * BK];  // [128 n][64 k]
  const int tid = threadIdx.x;
  const int m0 = blockIdx.x * BM;
  const int n0 = blockIdx.y * BN;
  const int wv = tid >> 6, l = tid & 63;
  const int wr = wv >> 1, wc = wv & 1;
  const int lrow = l & 15, lhi = l >> 4;

  f32x4 acc[4][4] = {};

  const int arow = tid >> 3;          // 0..31
  const int acb  = (tid & 7) << 4;    // byte col 0..112

#pragma unroll
  for (int s = 0; s < 4; ++s) {
    const int k0 = s * BK;
    // stage A
#pragma unroll
    for (int p = 0; p < 4; ++p) {
      int row = p * 32 + arow;
      int grow = m0 + row; if (grow >= M_NODES) grow = M_NODES - 1;
      int gcb = acb ^ ((row & 7) << 4);
      gload_lds16(h + (size_t)grow * D + k0 + (gcb >> 1), As + row * BK + (acb >> 1));
    }
    // stage B (Bt is [512][256], n-major)
#pragma unroll
    for (int p = 0; p < 4; ++p) {
      int row = p * 32 + arow;
      int gn = n0 + row;
      int gcb = acb ^ ((row & 7) << 4);
      gload_lds16(Bt + (size_t)gn * D + k0 + (gcb >> 1), Bs + row * BK + (acb >> 1));
    }
    __syncthreads();
#pragma unroll
    for (int kk = 0; kk < 2; ++kk) {
      bf16x8 af[4], bfr[4];
#pragma unroll
      for (int mi = 0; mi < 4; ++mi) {
        int row = wr * 64 + mi * 16 + lrow;
        int off = row * 128 + ((kk * 64 + lhi * 16) ^ ((row & 7) << 4));
        af[mi] = *(const bf16x8*)((const char*)As + off);
      }
#pragma unroll
      for (int nj = 0; nj < 4; ++nj) {
        int row = wc * 64 + nj * 16 + lrow;
        int off = row * 128 + ((kk * 64 + lhi * 16) ^ ((row & 7) << 4));
        bfr[nj] = *(const bf16x8*)((const char*)Bs + off);
      }
#pragma unroll
      for (int mi = 0; mi < 4; ++mi)
#pragma unroll
        for (int nj = 0; nj < 4; ++nj)
          acc[mi][nj] = __builtin_amdgcn_mfma_f32_16x16x32_bf16(af[mi], bfr[nj], acc[mi][nj], 0, 0, 0);
    }
    __syncthreads();
  }

  // epilogue: C/D map col=lane&15, row=(lane>>4)*4+reg
#pragma unroll
  for (int mi = 0; mi < 4; ++mi) {
#pragma unroll
    for (int nj = 0; nj < 4; ++nj) {
      int gc = n0 + wc * 64 + nj * 16 + lrow;
#pragma unroll
      for (int r = 0; r < 4; ++r) {
        int grow = m0 + wr * 64 + mi * 16 + lhi * 4 + r;
        if (grow < M_NODES)
          outAB[(size_t)grow * D2 + gc] = (ushort)f2bf(acc[mi][nj][r]);
      }
    }
  }
}

// ---------------- SpMM + selfterm + BN stats ----------------
// Half-wave row pairing: lanes 0-31 own row 2t, lanes 32-63 own row 2t+1.
// Each lane covers 8 bf16 cols (16B). Gathers are uint4 (16B/lane).
// FIX vs prev round: edge-batch loop bound is WAVE-UNIFORM (degmax of the
// pair), so every __shfl executes with all 64 lanes active (ds_bpermute from
// an inactive lane is undefined). Tail lanes use vv=0 + clamped dup gather.
#define SPMM_CHUNK 16

__global__ __launch_bounds__(256, 4)
void spmm_kernel(ushort* __restrict__ AB, const int* __restrict__ rp,
                 const int* __restrict__ e_col, const float* __restrict__ e_val,
                 float* __restrict__ stats) {
  __shared__ float sstats[2 * D];
  for (int i = threadIdx.x; i < 2 * D; i += 256) sstats[i] = 0.f;
  __syncthreads();

  const int wv = threadIdx.x >> 6, l = threadIdx.x & 63;
  const int hl = l >> 5, lc = l & 31;
  const int wave = blockIdx.x * 4 + wv;
  const int row0 = wave * SPMM_CHUNK;

  float s[8] = {}, q[8] = {};

  if (row0 < M_NODES) {
    // rowptr preload for chunk (lanes 0..16)
    int myrp = (l <= SPMM_CHUNK) ? rp[row0 + l] : 0;
    const int ebase = __shfl(myrp, 0);
    const int ecnt  = __shfl(myrp, SPMM_CHUNK) - ebase;
    // metadata preload: up to 128 edges register-resident
    int   myc0 = (l < ecnt)      ? e_col[ebase + l]      : 0;
    float myv0 = (l < ecnt)      ? e_val[ebase + l]      : 0.f;
    int   myc1 = (64 + l < ecnt) ? e_col[ebase + 64 + l] : 0;
    float myv1 = (64 + l < ecnt) ? e_val[ebase + 64 + l] : 0.f;

    for (int t = 0; t < SPMM_CHUNK; t += 2) {
      const int i = row0 + t + hl;                 // this half's row
      const int eA0 = __shfl(myrp, t);
      const int eA1 = __shfl(myrp, t + 1);
      const int eB1 = __shfl(myrp, t + 2);
      const int d0 = eA1 - eA0, d1 = eB1 - eA1;
      const int e0  = hl ? eA1 : eA0;
      const int deg = hl ? d1  : d0;
      const int degmax = (d0 > d1) ? d0 : d1;      // wave-uniform bound

      float a[8] = {};

      for (int b = 0; b < degmax; b += 4) {        // uniform: full wave active
        float vv[4]; uint4 sp[4];
#pragma unroll
        for (int j = 0; j < 4; ++j) {
          int ej = b + j;
          int ecl = (ej < deg) ? ej : ((deg > 0) ? deg - 1 : 0);  // clamp: dup gather
          int slot = e0 - ebase + ecl;
          int sl = slot & 63;
          int cA = __shfl(myc0, sl);
          int cB = __shfl(myc1, sl);
          float vA = __shfl(myv0, sl);
          float vB = __shfl(myv1, sl);
          int   c = (slot < 64) ? cA : cB;
          float v = (slot < 64) ? vA : vB;
          if (slot >= 128 && ej < deg) {           // statistically unreachable
            c = e_col[e0 + ecl]; v = e_val[e0 + ecl];
          }
          vv[j] = (ej < deg) ? v : 0.f;
          sp[j] = *(const uint4*)(AB + (size_t)c * D2 + lc * 8);
        }
#pragma unroll
        for (int j = 0; j < 4; ++j) {
          a[0] += vv[j] * bf2f(sp[j].x & 0xffff);
          a[1] += vv[j] * bf2f(sp[j].x >> 16);
          a[2] += vv[j] * bf2f(sp[j].y & 0xffff);
          a[3] += vv[j] * bf2f(sp[j].y >> 16);
          a[4] += vv[j] * bf2f(sp[j].z & 0xffff);
          a[5] += vv[j] * bf2f(sp[j].z >> 16);
          a[6] += vv[j] * bf2f(sp[j].w & 0xffff);
          a[7] += vv[j] * bf2f(sp[j].w >> 16);
        }
      }

      // self term + write-back (cols 256..511 of row i)
      const uint4 st = *(const uint4*)(AB + (size_t)i * D2 + D + lc * 8);
      a[0] += bf2f(st.x & 0xffff); a[1] += bf2f(st.x >> 16);
      a[2] += bf2f(st.y & 0xffff); a[3] += bf2f(st.y >> 16);
      a[4] += bf2f(st.z & 0xffff); a[5] += bf2f(st.z >> 16);
      a[6] += bf2f(st.w & 0xffff); a[7] += bf2f(st.w >> 16);

      uint4 o;
      o.x = f2bf(a[0]) | (f2bf(a[1]) << 16);
      o.y = f2bf(a[2]) | (f2bf(a[3]) << 16);
      o.z = f2bf(a[4]) | (f2bf(a[5]) << 16);
      o.w = f2bf(a[6]) | (f2bf(a[7]) << 16);
      *(uint4*)(AB + (size_t)i * D2 + D + lc * 8) = o;

#pragma unroll
      for (int k = 0; k < 8; ++k) { s[k] += a[k]; q[k] += a[k] * a[k]; }
    }
  }

  // block-level LDS reduction, then one global atomic per address per block
  const int c0 = lc * 8;
#pragma unroll
  for (int k = 0; k < 8; ++k) {
    atomicAdd(&sstats[c0 + k], s[k]);
    atomicAdd(&sstats[D + c0 + k], q[k]);
  }
  __syncthreads();
  atomicAdd(&stats[threadIdx.x], sstats[threadIdx.x]);
  atomicAdd(&stats[D + threadIdx.x], sstats[D + threadIdx.x]);
}

// ---------------- fused BN finalize + normalize + ReLU ----------------
// Each thread owns 8 columns; derives scale/shift once; processes 8 rows.
template<bool LAST>
__global__ void norm_kernel(const ushort* __restrict__ AB, const float* __restrict__ stats,
                            const float* __restrict__ gamma, const float* __restrict__ beta,
                            ushort* __restrict__ hout, float* __restrict__ out) {
  const int cs = threadIdx.x & 31;
  const int rr = threadIdx.x >> 5;   // 0..7
  const int c0 = cs * 8;

  float sc[8], sh[8];
#pragma unroll
  for (int k = 0; k < 8; ++k) {
    float mean = stats[c0 + k] * (1.0f / M_NODES);
    float var  = stats[D + c0 + k] * (1.0f / M_NODES) - mean * mean;
    float rstd = rsqrtf(var + 1e-5f);
    float g = gamma[c0 + k];
    sc[k] = g * rstd;
    sh[k] = beta[c0 + k] - mean * sc[k];
  }

  const int r0 = blockIdx.x * 64;
#pragma unroll
  for (int rb = 0; rb < 8; ++rb) {
    int r = r0 + rb * 8 + rr;
    if (r >= M_NODES) break;
    const uint4 u = *(const uint4*)(AB + (size_t)r * D2 + D + c0);
    float f[8];
    f[0] = bf2f(u.x & 0xffff); f[1] = bf2f(u.x >> 16);
    f[2] = bf2f(u.y & 0xffff); f[3] = bf2f(u.y >> 16);
    f[4] = bf2f(u.z & 0xffff); f[5] = bf2f(u.z >> 16);
    f[6] = bf2f(u.w & 0xffff); f[7] = bf2f(u.w >> 16);
#pragma unroll
    for (int k = 0; k < 8; ++k) f[k] = fmaxf(f[k] * sc[k] + sh[k], 0.f);
    if (LAST) {
      float4 r0v = { f[0], f[1], f[2], f[3] };
      float4 r1v = { f[4], f[5], f[6], f[7] };
      *(float4*)(out + (size_t)r * D2 + c0) = r0v;
      *(float4*)(out + (size_t)r * D2 + c0 + 4) = r1v;
    } else {
      uint4 o;
      o.x = f2bf(f[0]) | (f2bf(f[1]) << 16);
      o.y = f2bf(f[2]) | (f2bf(f[3]) << 16);
      o.z = f2bf(f[4]) | (f2bf(f[5]) << 16);
      o.w = f2bf(f[6]) | (f2bf(f[7]) << 16);
      *(uint4*)(hout + (size_t)r * D + c0) = o;
    }
  }
}

// ---------------- launch ----------------
extern "C" void kernel_launch(void* const* d_in, const int* in_sizes, int n_in,
                              void* d_out, int out_size, void* d_ws, size_t ws_size,
                              hipStream_t stream) {
  const float* x      = (const float*)d_in[0];
  const float* vals   = (const float*)d_in[1];
  const float* W      = (const float*)d_in[2];
  const float* SW     = (const float*)d_in[3];
  const float* gammas = (const float*)d_in[4];
  const float* betas  = (const float*)d_in[5];
  const int*   rows   = (const int*)d_in[6];
  const int*   cols   = (const int*)d_in[7];
  float* out = (float*)d_out;

  char* ws = (char*)d_ws;
  size_t off = 0;
  auto alloc = [&](size_t bytes) {
    void* p = ws + off;
    off = (off + bytes + 255) & ~(size_t)255;
    return p;
  };
  ushort* h    = (ushort*)alloc((size_t)M_NODES * D * 2);
  ushort* AB   = (ushort*)alloc((size_t)M_NODES * D2 * 2);
  ushort* Bt   = (ushort*)alloc((size_t)NLAYERS * D2 * D * 2);
  int*   rp    = (int*)alloc((M_NODES + 1) * 4);
  int*   cursor= (int*)alloc((M_NODES + 1) * 4);
  int*   e_col = (int*)alloc(NE * 4);
  float* e_val = (float*)alloc(NE * 4);
  int*   bsum  = (int*)alloc(512);
  int*   boff  = (int*)alloc(512);
  float* stats = (float*)alloc(NLAYERS * 2 * D * 4);

  hipMemsetAsync(cursor, 0, (size_t)M_NODES * 4, stream);  // counts
  hipMemsetAsync(stats, 0, (size_t)NLAYERS * 2 * D * 4, stream);

  hist_kernel<<<(NE + 255) / 256, 256, 0, stream>>>(rows, cursor);
  scan1_kernel<<<98, 256, 0, stream>>>(cursor, rp, bsum);
  scan2_kernel<<<1, 128, 0, stream>>>(bsum, boff);
  scan3_kernel<<<(M_NODES + 256) / 256, 256, 0, stream>>>(rp, boff, cursor);
  scatter_kernel<<<(NE + 255) / 256, 256, 0, stream>>>(rows, cols, vals, cursor, e_col, e_val);

  prep_x_kernel<<<(M_NODES * D / 4) / 256, 256, 0, stream>>>(x, h, out);
  conv_w_kernel<<<(NLAYERS * D2 * D) / 256, 256, 0, stream>>>(W, SW, Bt);

  const int spmm_blocks = (M_NODES + SPMM_CHUNK * 4 - 1) / (SPMM_CHUNK * 4);
  const int norm_blocks = (M_NODES + 63) / 64;
  for (int lyr = 0; lyr < NLAYERS; ++lyr) {
    gemm_kernel<<<dim3((M_NODES + BM - 1) / BM, D2 / BN), 256, 0, stream>>>(
        h, Bt + (size_t)lyr * D2 * D, AB);
    spmm_kernel<<<spmm_blocks, 256, 0, stream>>>(AB, rp, e_col, e_val,
                                                 stats + (size_t)lyr * 2 * D);
    if (lyr < NLAYERS - 1)
      norm_kernel<false><<<norm_blocks, 256, 0, stream>>>(
          AB, stats + (size_t)lyr * 2 * D, gammas + lyr * D, betas + lyr * D, h, nullptr);
    else
      norm_kernel<true><<<norm_blocks, 256, 0, stream>>>(
          AB, stats + (size_t)lyr * 2 * D, gammas + lyr * D, betas + lyr * D, nullptr, out);
  }
}